// Round 15
// baseline (172.022 us; speedup 1.0000x reference)
//
#include <hip/hip_runtime.h>
#include <math.h>

#define NOBS 7
#define PI_F 3.14159265358979f

// ---- Round 25: R24 + te_w1 added to the warm-up set ----
// R24's HBM->L2 weight warm-up gained ~3us (121.3 -> 118.3 harness).
// It omitted te_w1 (1024 lines), consumed FIRST at MLP layer 1 with
// ~2-3us of phase0+emb lead time. Extended map: te_w1 + te_w2 + ip_w1 +
// ip_w2 = 10240 lines, 1/32 partition per block-group (mod-8 XCD
// round-robin heuristic), 2 dword loads/thread (covers 320-line chunk),
// sunk before the circuit. Everything else R24/R21 verbatim.

typedef float v2f __attribute__((ext_vector_type(2)));

__device__ __forceinline__ v2f pk_mul(v2f a, v2f b) {
  v2f d;
  asm("v_pk_mul_f32 %0, %1, %2" : "=v"(d) : "v"(a), "v"(b));
  return d;
}
__device__ __forceinline__ v2f pk_fma(v2f a, v2f b, v2f c) {
  v2f d;
  asm("v_pk_fma_f32 %0, %1, %2, %3" : "=v"(d) : "v"(a), "v"(b), "v"(c));
  return d;
}

// ---- VALU-only cross-lane xor exchange ----
template<int LM>
__device__ __forceinline__ float lane_partner(float x) {
  if constexpr (LM == 1) {
    return __int_as_float(__builtin_amdgcn_mov_dpp(__float_as_int(x), 0xB1, 0xF, 0xF, true));
  } else if constexpr (LM == 2) {
    return __int_as_float(__builtin_amdgcn_mov_dpp(__float_as_int(x), 0x4E, 0xF, 0xF, true));
  } else if constexpr (LM == 4) {
    int a = __builtin_amdgcn_mov_dpp(__float_as_int(x), 0x1B, 0xF, 0xF, true);   // xor3
    return __int_as_float(__builtin_amdgcn_mov_dpp(a, 0x141, 0xF, 0xF, true));   // xor7 -> net xor4
  } else if constexpr (LM == 8) {
    int a = __builtin_amdgcn_mov_dpp(__float_as_int(x), 0x141, 0xF, 0xF, true);  // xor7
    return __int_as_float(__builtin_amdgcn_mov_dpp(a, 0x140, 0xF, 0xF, true));   // xor15 -> net xor8
  } else if constexpr (LM == 16) {
#if __has_builtin(__builtin_amdgcn_permlane16_swap)
    unsigned xu = __float_as_uint(x);
    auto r = __builtin_amdgcn_permlane16_swap(xu, xu, false, false);
    return (__uint_as_float(r[0]) + __uint_as_float(r[1])) - x;
#else
    return __shfl_xor(x, 16, 64);
#endif
  } else {
#if __has_builtin(__builtin_amdgcn_permlane32_swap)
    unsigned xu = __float_as_uint(x);
    auto r = __builtin_amdgcn_permlane32_swap(xu, xu, false, false);
    return (__uint_as_float(r[0]) + __uint_as_float(r[1])) - x;
#else
    return __shfl_xor(x, 32, 64);
#endif
  }
}

template<int LM>
__device__ __forceinline__ float xor_sum(float x) {
  if constexpr (LM == 16) {
#if __has_builtin(__builtin_amdgcn_permlane16_swap)
    unsigned xu = __float_as_uint(x);
    auto r = __builtin_amdgcn_permlane16_swap(xu, xu, false, false);
    return __uint_as_float(r[0]) + __uint_as_float(r[1]);
#else
    return x + __shfl_xor(x, 16, 64);
#endif
  } else if constexpr (LM == 32) {
#if __has_builtin(__builtin_amdgcn_permlane32_swap)
    unsigned xu = __float_as_uint(x);
    auto r = __builtin_amdgcn_permlane32_swap(xu, xu, false, false);
    return __uint_as_float(r[0]) + __uint_as_float(r[1]);
#else
    return x + __shfl_xor(x, 32, 64);
#endif
  } else {
    return x + lane_partner<LM>(x);
  }
}

__device__ __forceinline__ float rdlane(float v, int idx) {
  return __int_as_float(__builtin_amdgcn_readlane(__float_as_int(v), idx));
}

__device__ __forceinline__ float2 cmul(float2 a, float2 b) {
  return make_float2(a.x*b.x - a.y*b.y, a.x*b.y + a.y*b.x);
}
__device__ __forceinline__ float2 cmulc(float2 a, float2 b) {  // a * conj(b)
  return make_float2(a.x*b.x + a.y*b.y, a.y*b.x - a.x*b.y);
}
__device__ __forceinline__ float2 cadd(float2 a, float2 b) {
  return make_float2(a.x + b.x, a.y + b.y);
}

struct SV { v2f q[4]; };   // q[r] = (re, im)

// ---------------- gate helpers (4 complex amps/lane, packed math) ----------------

template<int W>
__device__ __forceinline__ void ry_lane4(v2f* vv, int lane,
                                         float ct, float st, int idx, float sg) {
  float c = rdlane(ct, idx), s = sg * rdlane(st, idx);
  constexpr int LM = 1 << (5 - W);
  const float ls = (lane & LM) ? s : -s;
  v2f c2 = {c, c}, ls2 = {ls, ls};
#pragma unroll
  for (int r = 0; r < 4; ++r) {
    v2f p;
    p.x = lane_partner<LM>(vv[r].x);
    p.y = lane_partner<LM>(vv[r].y);
    vv[r] = pk_fma(ls2, p, pk_mul(c2, vv[r]));
  }
}

__device__ __forceinline__ void ry_reg6(v2f* vv, float ct, float st, int idx, float sg) {
  float c = rdlane(ct, idx), s = sg * rdlane(st, idx);
  v2f c2 = {c, c}, s2 = {s, s}, ns2 = {-s, -s};
#pragma unroll
  for (int k = 0; k < 2; ++k) {
    v2f a0 = vv[k], a1 = vv[k + 2];
    vv[k]     = pk_fma(ns2, a1, pk_mul(c2, a0));
    vv[k + 2] = pk_fma(s2,  a0, pk_mul(c2, a1));
  }
}

__device__ __forceinline__ void ry_reg7(v2f* vv, float ct, float st, int idx, float sg) {
  float c = rdlane(ct, idx), s = sg * rdlane(st, idx);
  v2f c2 = {c, c}, s2 = {s, s}, ns2 = {-s, -s};
#pragma unroll
  for (int k = 0; k < 4; k += 2) {
    v2f a0 = vv[k], a1 = vv[k + 1];
    vv[k]     = pk_fma(ns2, a1, pk_mul(c2, a0));
    vv[k + 1] = pk_fma(s2,  a0, pk_mul(c2, a1));
  }
}

template<int C, int T>
__device__ __forceinline__ void crx_ll4(v2f* vv, int lane,
                                        float ct, float st, int idx, float sg) {
  float c = rdlane(ct, idx), s = sg * rdlane(st, idx);
  constexpr int LC = 1 << (5 - C), LT = 1 << (5 - T);
  const bool act = (lane & LC) != 0;
  const float cp = act ? c : 1.f, sp = act ? s : 0.f;
  v2f cp2 = {cp, cp}, ssp2 = {sp, -sp};
#pragma unroll
  for (int r = 0; r < 4; ++r) {
    v2f p;
    p.x = lane_partner<LT>(vv[r].y);   // partner imag
    p.y = lane_partner<LT>(vv[r].x);   // partner real
    vv[r] = pk_fma(ssp2, p, pk_mul(cp2, vv[r]));
  }
}

template<int RB, int T>
__device__ __forceinline__ void crx_rc_lane(v2f* vv,
                                            float ct, float st, int idx, float sg) {
  float c = rdlane(ct, idx), s = sg * rdlane(st, idx);
  constexpr int LT = 1 << (5 - T);
  v2f c2 = {c, c}, ss2 = {s, -s};
#pragma unroll
  for (int r = 0; r < 4; ++r) {
    if (r & RB) {
      v2f p;
      p.x = lane_partner<LT>(vv[r].y);
      p.y = lane_partner<LT>(vv[r].x);
      vv[r] = pk_fma(ss2, p, pk_mul(c2, vv[r]));
    }
  }
}

template<int C, int TB>
__device__ __forceinline__ void crx_lc_reg(v2f* vv, int lane,
                                           float ct, float st, int idx, float sg) {
  float c = rdlane(ct, idx), s = sg * rdlane(st, idx);
  constexpr int LC = 1 << (5 - C);
  const bool act = (lane & LC) != 0;
  const float cp = act ? c : 1.f, sp = act ? s : 0.f;
  v2f cp2 = {cp, cp}, ssp2 = {sp, -sp};
#pragma unroll
  for (int x = 0; x < 4; ++x) {
    if (!(x & TB)) {
      const int y = x | TB;
      v2f ox = vv[x], oy = vv[y];
      v2f swx = {ox.y, ox.x}, swy = {oy.y, oy.x};
      vv[x] = pk_fma(ssp2, swy, pk_mul(cp2, ox));
      vv[y] = pk_fma(ssp2, swx, pk_mul(cp2, oy));
    }
  }
}

template<int CB, int TB>
__device__ __forceinline__ void crx_rr(v2f* vv,
                                       float ct, float st, int idx, float sg) {
  float c = rdlane(ct, idx), s = sg * rdlane(st, idx);
  constexpr int x = CB, y = CB | TB;
  v2f c2 = {c, c}, ss2 = {s, -s};
  v2f ox = vv[x], oy = vv[y];
  v2f swx = {ox.y, ox.x}, swy = {oy.y, oy.x};
  vv[x] = pk_fma(ss2, swy, pk_mul(c2, ox));
  vv[y] = pk_fma(ss2, swx, pk_mul(c2, oy));
}

// ---------------- sim14 layers: force-inlined (R3 structure) ----------------

__device__ __forceinline__ SV sim14_fwd(SV v, float ct, float st, int off) {
  const int lane = threadIdx.x & 63;
  v2f* vv = v.q;
  const float sg = 1.f;
  ry_lane4<0>(vv,lane,ct,st,off+0,sg); ry_lane4<1>(vv,lane,ct,st,off+1,sg);
  ry_lane4<2>(vv,lane,ct,st,off+2,sg); ry_lane4<3>(vv,lane,ct,st,off+3,sg);
  ry_lane4<4>(vv,lane,ct,st,off+4,sg); ry_lane4<5>(vv,lane,ct,st,off+5,sg);
  ry_reg6(vv,ct,st,off+6,sg);
  ry_reg7(vv,ct,st,off+7,sg);
  crx_rc_lane<1,0>(vv,ct,st,off+8,sg);        // (7,0)
  crx_rr<2,1>(vv,ct,st,off+9,sg);             // (6,7)
  crx_lc_reg<5,2>(vv,lane,ct,st,off+10,sg);   // (5,6)
  crx_ll4<4,5>(vv,lane,ct,st,off+11,sg); crx_ll4<3,4>(vv,lane,ct,st,off+12,sg);
  crx_ll4<2,3>(vv,lane,ct,st,off+13,sg); crx_ll4<1,2>(vv,lane,ct,st,off+14,sg);
  crx_ll4<0,1>(vv,lane,ct,st,off+15,sg);
  ry_lane4<0>(vv,lane,ct,st,off+16,sg); ry_lane4<1>(vv,lane,ct,st,off+17,sg);
  ry_lane4<2>(vv,lane,ct,st,off+18,sg); ry_lane4<3>(vv,lane,ct,st,off+19,sg);
  ry_lane4<4>(vv,lane,ct,st,off+20,sg); ry_lane4<5>(vv,lane,ct,st,off+21,sg);
  ry_reg6(vv,ct,st,off+22,sg);
  ry_reg7(vv,ct,st,off+23,sg);
  crx_rr<1,2>(vv,ct,st,off+24,sg);            // (7,6)
  crx_lc_reg<0,1>(vv,lane,ct,st,off+25,sg);   // (0,7)
  crx_ll4<1,0>(vv,lane,ct,st,off+26,sg); crx_ll4<2,1>(vv,lane,ct,st,off+27,sg);
  crx_ll4<3,2>(vv,lane,ct,st,off+28,sg); crx_ll4<4,3>(vv,lane,ct,st,off+29,sg);
  crx_ll4<5,4>(vv,lane,ct,st,off+30,sg);
  crx_rc_lane<2,5>(vv,ct,st,off+31,sg);       // (6,5)
  return v;
}

__device__ __forceinline__ SV sim14_adj(SV v, float ct, float st, int off) {
  const int lane = threadIdx.x & 63;
  v2f* vv = v.q;
  const float sg = -1.f;
  crx_rc_lane<2,5>(vv,ct,st,off+31,sg);       // (6,5)
  crx_ll4<5,4>(vv,lane,ct,st,off+30,sg); crx_ll4<4,3>(vv,lane,ct,st,off+29,sg);
  crx_ll4<3,2>(vv,lane,ct,st,off+28,sg); crx_ll4<2,1>(vv,lane,ct,st,off+27,sg);
  crx_ll4<1,0>(vv,lane,ct,st,off+26,sg);
  crx_lc_reg<0,1>(vv,lane,ct,st,off+25,sg);   // (0,7)
  crx_rr<1,2>(vv,ct,st,off+24,sg);            // (7,6)
  ry_reg7(vv,ct,st,off+23,sg);
  ry_reg6(vv,ct,st,off+22,sg);
  ry_lane4<5>(vv,lane,ct,st,off+21,sg); ry_lane4<4>(vv,lane,ct,st,off+20,sg);
  ry_lane4<3>(vv,lane,ct,st,off+19,sg); ry_lane4<2>(vv,lane,ct,st,off+18,sg);
  ry_lane4<1>(vv,lane,ct,st,off+17,sg); ry_lane4<0>(vv,lane,ct,st,off+16,sg);
  crx_ll4<0,1>(vv,lane,ct,st,off+15,sg); crx_ll4<1,2>(vv,lane,ct,st,off+14,sg);
  crx_ll4<2,3>(vv,lane,ct,st,off+13,sg); crx_ll4<3,4>(vv,lane,ct,st,off+12,sg);
  crx_ll4<4,5>(vv,lane,ct,st,off+11,sg);
  crx_lc_reg<5,2>(vv,lane,ct,st,off+10,sg);   // (5,6)
  crx_rr<2,1>(vv,ct,st,off+9,sg);             // (6,7)
  crx_rc_lane<1,0>(vv,ct,st,off+8,sg);        // (7,0)
  ry_reg7(vv,ct,st,off+7,sg);
  ry_reg6(vv,ct,st,off+6,sg);
  ry_lane4<5>(vv,lane,ct,st,off+5,sg); ry_lane4<4>(vv,lane,ct,st,off+4,sg);
  ry_lane4<3>(vv,lane,ct,st,off+3,sg); ry_lane4<2>(vv,lane,ct,st,off+2,sg);
  ry_lane4<1>(vv,lane,ct,st,off+1,sg); ry_lane4<0>(vv,lane,ct,st,off+0,sg);
  return v;
}

// ---------------- cooperative-row MLP layer, depth-D weight pipeline (R21) ----------------

template<int IN, int NP, int MODE, int D>
__device__ __forceinline__ void mlp_layer(const float* __restrict__ W,
    const float* __restrict__ bias, const float* xl, float* yl,
    int rbase, int lane)
{
  const int sub = lane & 7;
  const int g   = lane >> 3;
  constexpr int NIT = IN / 32;
  const float4* x4 = (const float4*)xl + sub;
  float4 e[NIT];
#pragma unroll
  for (int it = 0; it < NIT; ++it) e[it] = x4[it * 8];

  float4 wbuf[D][NIT];
#pragma unroll
  for (int d = 0; d < D; ++d) {
    const float4* wp = (const float4*)(W + (rbase + d * 8 + g) * IN) + sub;
#pragma unroll
    for (int it = 0; it < NIT; ++it) wbuf[d][it] = wp[it * 8];
  }

#pragma unroll
  for (int p = 0; p < NP; ++p) {
    constexpr int DD = D;   // keep p % DD compile-time under unroll
    v2f acc2 = {0.f, 0.f};
#pragma unroll
    for (int it = 0; it < NIT; ++it) {
      float4 w = wbuf[p % DD][it];
      v2f wa = {w.x, w.y}, wb = {w.z, w.w};
      v2f ea = {e[it].x, e[it].y}, eb = {e[it].z, e[it].w};
      acc2 = pk_fma(wa, ea, acc2);
      acc2 = pk_fma(wb, eb, acc2);
    }
    if (p + D < NP) {
      const float4* wn = (const float4*)(W + (rbase + (p + D) * 8 + g) * IN) + sub;
#pragma unroll
      for (int it = 0; it < NIT; ++it) wbuf[p % DD][it] = wn[it * 8];
    }
    float acc = acc2.x + acc2.y;
    acc = xor_sum<1>(acc);
    acc = xor_sum<2>(acc);
    acc = xor_sum<4>(acc);
    if (sub == 0) {
      const int row = rbase + p * 8 + g;
      float a = acc + bias[row];
      if constexpr (MODE == 0) {
        yl[row] = a / (1.f + __expf(-a));
      } else if constexpr (MODE == 1) {
        yl[row] = a;
      } else {
        float th = PI_F / (1.f + __expf(-a));   // theta/2 = pi * sigmoid(a)
        float sn, cn;
        __sincosf(th, &sn, &cn);
        ((float2*)yl)[row] = make_float2(cn, sn);
      }
    }
  }
}

// ---------------- main kernel: 256 threads = 4 waves, one batch elem/block ----------------

__global__ __launch_bounds__(256, 1) void qsvt_kernel(
    const float* __restrict__ z_t, const float* __restrict__ t,
    const float* __restrict__ te_w1, const float* __restrict__ te_b1,
    const float* __restrict__ te_w2, const float* __restrict__ te_b2,
    const float* __restrict__ ip_w1, const float* __restrict__ ip_b1,
    const float* __restrict__ ip_w2, const float* __restrict__ ip_b2,
    const float* __restrict__ prep_p, const float* __restrict__ sig,
    const float* __restrict__ qff,
    const float* __restrict__ A_obs, const float* __restrict__ B_obs,
    const float* __restrict__ D_obs,
    const float* __restrict__ head_w, const float* __restrict__ head_b,
    float* __restrict__ out)
{
  __shared__ __align__(16) float emb[128];
  __shared__ __align__(16) float y1[128];
  __shared__ __align__(16) float hbuf[256];
  __shared__ __align__(16) float h1[256];
  __shared__ __align__(16) float2 seltab[256];   // [s*64+g] -> (cos(th/2), sin(th/2))
  __shared__ __align__(16) float2 qtab2[32];
  __shared__ __align__(16) float2 sX1[16], sX2[16], sF[16], sa0[4];
  __shared__ __align__(16) float dumpR[4][256];
  __shared__ __align__(16) float dumpI[4][256];
  __shared__ float redbuf[NOBS][4];
  __shared__ float hdc[NOBS][3], hxc[NOBS][6], hyc[NOBS][6];
  __shared__ __align__(16) float shw[128 * NOBS];
  __shared__ __align__(16) float shb[128];
  extern __shared__ float4 dxw[];                // 2 x (256 R + 256 I) float4 = 16 KB

  const int tid  = threadIdx.x;
  const int lane = tid & 63;
  const int wv   = tid >> 6;   // 0..3
  const int s    = wv;         // ancilla value == wave
  const int b    = blockIdx.x;

  // ===== R25: early weight warm-up (HBM->L2, overlapped with phase0+emb) =====
  // 10240 cachelines: te_w1 (1024) + te_w2 (1024) + ip_w1 (4096) + ip_w2
  // (4096). 1/32 partition (320 lines) per block-group under mod-8 XCD
  // round-robin (perf heuristic only); 2 dword loads/thread covers it.
  float wtmp0, wtmp1;
  {
    const int chunk = (blockIdx.x >> 3) & 31;
    int l0 = chunk * 320 + tid;
    int l1 = l0 + 64;            // tid 0..255 + 64 -> union covers 0..319
    const float* a0;
    const float* a1;
    a0 = (l0 < 1024) ? (te_w1 + (l0 << 4))
       : (l0 < 2048) ? (te_w2 + ((l0 - 1024) << 4))
       : (l0 < 6144) ? (ip_w1 + ((l0 - 2048) << 4))
                     : (ip_w2 + ((l0 - 6144) << 4));
    a1 = (l1 < 1024) ? (te_w1 + (l1 << 4))
       : (l1 < 2048) ? (te_w2 + ((l1 - 1024) << 4))
       : (l1 < 6144) ? (ip_w1 + ((l1 - 2048) << 4))
                     : (ip_w2 + ((l1 - 6144) << 4));
    wtmp0 = *a0;
    wtmp1 = *a1;
  }

  // ===== Phase 0: wave 0 builds block-invariant ancilla matrices into LDS =====
  if (tid < 32) {
    float sn, cn;
    __sincosf(0.5f * qff[tid], &sn, &cn);
    qtab2[tid] = make_float2(cn, sn);
  }
  if (wv == 0) {
    float2 Ga[2][2][2], Gb[2][2][2];
    for (int ly = 0; ly < 2; ++ly)
      for (int qi = 0; qi < 2; ++qi) {
        float y = prep_p[ly*4 + qi*2 + 0], z = prep_p[ly*4 + qi*2 + 1];
        float cy, sy, cz, sz;
        __sincosf(0.5f*y, &sy, &cy);
        __sincosf(0.5f*z, &sz, &cz);
        float2 g00 = make_float2( cy*cz, -cy*sz);
        float2 g01 = make_float2(-sy*cz,  sy*sz);
        float2 g10 = make_float2( sy*cz,  sy*sz);
        float2 g11 = make_float2( cy*cz,  cy*sz);
        if (qi == 0) { Ga[ly][0][0]=g00; Ga[ly][0][1]=g01; Ga[ly][1][0]=g10; Ga[ly][1][1]=g11; }
        else         { Gb[ly][0][0]=g00; Gb[ly][0][1]=g01; Gb[ly][1][0]=g10; Gb[ly][1][1]=g11; }
      }
    float2 M[2][4][4];
    for (int ly = 0; ly < 2; ++ly) {
      float2 T[4][4];
      for (int i = 0; i < 4; ++i)
        for (int j = 0; j < 4; ++j)
          T[i][j] = cmul(Ga[ly][i>>1][j>>1], Gb[ly][i&1][j&1]);
      for (int j = 0; j < 4; ++j) {
        M[ly][0][j] = T[0][j]; M[ly][1][j] = T[1][j];
        M[ly][2][j] = T[3][j]; M[ly][3][j] = T[2][j];
      }
    }
    float2 U[4][4];
    for (int i = 0; i < 4; ++i)
      for (int j = 0; j < 4; ++j) {
        float2 acc = make_float2(0.f, 0.f);
        for (int kk = 0; kk < 4; ++kk) acc = cadd(acc, cmul(M[1][i][kk], M[0][kk][j]));
        U[i][j] = acc;
      }
    float c0n, s0n, c1, s1v, c2, s2v, c3, s3v;
    __sincosf(sig[0], &s0n, &c0n);
    __sincosf(sig[1], &s1v, &c1);
    __sincosf(sig[2], &s2v, &c2);
    __sincosf(sig[3], &s3v, &c3);
    if (lane < 16) {
      int i = lane >> 2, j = lane & 3;   // i = s (row), j = sp (col)
      float2 a1 = make_float2(0.f, 0.f), a2 = make_float2(0.f, 0.f);
      for (int k = 0; k < 4; ++k) {
        float2 tt = cmulc(U[i][k], U[j][k]);
        float sk = (k == 0) ? 1.f : -1.f;
        a1 = cadd(a1, cmul(tt, make_float2(c1, sk*s1v)));
        a2 = cadd(a2, cmul(tt, make_float2(c2, sk*s2v)));
      }
      sX1[lane] = a1;
      sX2[lane] = a2;
      float2 d3 = make_float2(c3, (i == 0) ? s3v : -s3v);
      sF[lane] = cmul(d3, make_float2(U[j][i].x, -U[j][i].y));
    }
    if (lane < 4) sa0[lane] = cmul(U[lane][0], make_float2(c0n, s0n));
  }

  // ===== Phase A: MLP (cooperative rows, 4 waves) =====
  if (tid < 128) {
    float fr = __expf(-9.210340371976184f * (float)(tid & 63) / 64.f);
    float arg = t[b] * fr;
    float sn, cn;
    __sincosf(arg, &sn, &cn);
    emb[tid] = (tid < 64) ? cn : sn;
  }
  __syncthreads();

  mlp_layer<128, 4, 0, 4>(te_w1, te_b1, emb, y1, wv * 32, lane);
  if (tid < 128) hbuf[tid] = z_t[b * 128 + tid];
  __syncthreads();

  mlp_layer<128, 4, 1, 4>(te_w2, te_b2, y1, hbuf + 128, wv * 32, lane);
  __syncthreads();

  mlp_layer<256, 8, 0, 3>(ip_w1, ip_b1, hbuf, h1, wv * 64, lane);
  __syncthreads();

  mlp_layer<256, 8, 2, 3>(ip_w2, ip_b2, h1, (float*)seltab, wv * 64, lane);

  // prefetch observable + head coefficients into LDS (off the tail path)
  if (tid < NOBS * 6)      { hxc[tid/6][tid%6] = A_obs[tid]; hyc[tid/6][tid%6] = B_obs[tid]; }
  else if (tid >= 64 && tid < 64 + NOBS*3) { int q = tid - 64; hdc[q/3][q%3] = 2.f * D_obs[(q/3)*4 + (q%3) + 1]; }
#pragma unroll
  for (int i = tid; i < 128*NOBS; i += 256) shw[i] = head_w[i];
  if (tid < 128) shb[tid] = head_b[tid];
  __syncthreads();  // seltab/coefs/matrices visible to all waves

  // per-wave angle tables in registers (lane g <-> gate g)
  float2 mycs = seltab[(s << 6) | lane];
  float selc = mycs.x, sels = mycs.y;
  float2 myq = qtab2[lane & 31];
  float qc = myq.x, qs = myq.y;

  // R25: sink the warm-up loads (long since completed)
  asm volatile("" :: "v"(wtmp0), "v"(wtmp1));

  // ===== Phase C: circuit. init = U*D0*|0..0> : only m=0 (lane0, r0) nonzero =====
  SV v;
#pragma unroll
  for (int r = 0; r < 4; ++r) { v.q[r].x = 0.f; v.q[r].y = 0.f; }
  if (lane == 0) {
    float2 a0 = sa0[s];
    v.q[0].x = a0.x; v.q[0].y = a0.y;
  }

  // ancilla mix through the parity-alternating exchange buffer (1 barrier each)
  auto ancmix = [&](const float2* R, int site) {
    float4* bufR = dxw + (site & 1) * 512;
    float4* bufI = bufR + 256;
    bufR[wv * 64 + lane] = make_float4(v.q[0].x, v.q[1].x, v.q[2].x, v.q[3].x);
    bufI[wv * 64 + lane] = make_float4(v.q[0].y, v.q[1].y, v.q[2].y, v.q[3].y);
    __syncthreads();
    float outr[4] = {0.f, 0.f, 0.f, 0.f}, outi[4] = {0.f, 0.f, 0.f, 0.f};
#pragma unroll
    for (int sp = 0; sp < 4; ++sp) {
      float4 Pr = bufR[sp * 64 + lane];
      float4 Pi = bufI[sp * 64 + lane];
      float2 Rr = R[sp];
      outr[0] += Rr.x*Pr.x - Rr.y*Pi.x;  outi[0] += Rr.x*Pi.x + Rr.y*Pr.x;
      outr[1] += Rr.x*Pr.y - Rr.y*Pi.y;  outi[1] += Rr.x*Pi.y + Rr.y*Pr.y;
      outr[2] += Rr.x*Pr.z - Rr.y*Pi.z;  outi[2] += Rr.x*Pi.z + Rr.y*Pr.z;
      outr[3] += Rr.x*Pr.w - Rr.y*Pi.w;  outi[3] += Rr.x*Pi.w + Rr.y*Pr.w;
    }
#pragma unroll
    for (int r = 0; r < 4; ++r) { v.q[r].x = outr[r]; v.q[r].y = outi[r]; }
  };
  // buffer-reuse safety: site 2 rewrites buffer 0 only after site 1's barrier,
  // which every wave reached after consuming its site-0 reads -> race-free.

  v = sim14_fwd(v, selc, sels, 0);
  v = sim14_fwd(v, selc, sels, 32);
  ancmix(&sX1[s << 2], 0);
  v = sim14_adj(v, selc, sels, 32);
  v = sim14_adj(v, selc, sels, 0);
  ancmix(&sX2[s << 2], 1);
  v = sim14_fwd(v, selc, sels, 0);
  v = sim14_fwd(v, selc, sels, 32);
  ancmix(&sF[s << 2], 2);
  v = sim14_fwd(v, qc, qs, 0);

  // ===== Phase D: dump state, observables =====
  // each wave writes and reads ONLY its own s-row -> intra-wave lgkmcnt
  // ordering suffices, no barrier needed before the obs reads.
  *(float4*)&dumpR[s][lane << 2] = make_float4(v.q[0].x, v.q[1].x, v.q[2].x, v.q[3].x);
  *(float4*)&dumpI[s][lane << 2] = make_float4(v.q[0].y, v.q[1].y, v.q[2].y, v.q[3].y);

#pragma unroll
  for (int w = 0; w < NOBS; ++w) {
    const int pb = 6 - w;  // wires (w, w+1) -> bits (7-w, 6-w) of m
    int g = lane;
    int ib = ((g >> pb) << (pb + 2)) | (g & ((1 << pb) - 1));
    float xr[4], xi[4];
#pragma unroll
    for (int i = 0; i < 4; ++i) { xr[i] = dumpR[s][ib + (i << pb)]; xi[i] = dumpI[s][ib + (i << pb)]; }
    float a = hdc[w][0] * (xr[0]*xr[0] + xi[0]*xi[0])
            + hdc[w][1] * (xr[1]*xr[1] + xi[1]*xi[1])
            + hdc[w][2] * (xr[2]*xr[2] + xi[2]*xi[2]);
    const int oi[6] = {1, 2, 2, 3, 3, 3};
    const int oj[6] = {0, 0, 1, 0, 1, 2};
#pragma unroll
    for (int k2 = 0; k2 < 6; ++k2) {
      int i = oi[k2], j = oj[k2];
      float rr = xr[i]*xr[j] + xi[i]*xi[j];   // Re(conj(v_i) v_j)
      float ii = xr[i]*xi[j] - xi[i]*xr[j];   // Im(conj(v_i) v_j)
      a += 2.f * (hxc[w][k2]*rr - hyc[w][k2]*ii);
    }
    a = xor_sum<32>(a);
    a = xor_sum<16>(a);
    a = xor_sum<8>(a);
    a = xor_sum<4>(a);
    a = xor_sum<2>(a);
    a = xor_sum<1>(a);
    if (lane == 0) redbuf[w][s] = a;
  }
  __syncthreads();

  // ===== Phase E: head =====
  if (tid < 128) {
    float acc = shb[tid];
#pragma unroll
    for (int w = 0; w < NOBS; ++w) {
      float ev = redbuf[w][0] + redbuf[w][1] + redbuf[w][2] + redbuf[w][3];
      acc += ev * shw[tid*NOBS + w];
    }
    out[b * 128 + tid] = acc;
  }
}

extern "C" void kernel_launch(void* const* d_in, const int* in_sizes, int n_in,
                              void* d_out, int out_size, void* d_ws, size_t ws_size,
                              hipStream_t stream) {
  (void)n_in; (void)out_size; (void)d_ws; (void)ws_size;
  const float* z_t    = (const float*)d_in[0];
  const float* t      = (const float*)d_in[1];
  const float* te_w1  = (const float*)d_in[2];
  const float* te_b1  = (const float*)d_in[3];
  const float* te_w2  = (const float*)d_in[4];
  const float* te_b2  = (const float*)d_in[5];
  const float* ip_w1  = (const float*)d_in[6];
  const float* ip_b1  = (const float*)d_in[7];
  const float* ip_w2  = (const float*)d_in[8];
  const float* ip_b2  = (const float*)d_in[9];
  const float* prep_p = (const float*)d_in[10];
  const float* sig    = (const float*)d_in[11];
  const float* qff    = (const float*)d_in[12];
  const float* A_obs  = (const float*)d_in[13];
  const float* B_obs  = (const float*)d_in[14];
  const float* D_obs  = (const float*)d_in[15];
  const float* head_w = (const float*)d_in[16];
  const float* head_b = (const float*)d_in[17];
  float* out = (float*)d_out;

  int B = in_sizes[1];  // t is (B,)
  size_t dyn = 2 * 512 * sizeof(float4);
  qsvt_kernel<<<B, 256, dyn, stream>>>(
      z_t, t, te_w1, te_b1, te_w2, te_b2, ip_w1, ip_b1, ip_w2, ip_b2,
      prep_p, sig, qff, A_obs, B_obs, D_obs, head_w, head_b, out);
}

// Round 16
// 118.227 us; speedup vs baseline: 1.4550x; 1.4550x over previous
//
#include <hip/hip_runtime.h>
#include <math.h>

#define NOBS 7
#define PI_F 3.14159265358979f

// ---- Round 26: REVERT to R24 champion (118.3us) verbatim ----
// R25 (te_w1 warm extension) came back 3x slower with IDENTICAL
// fetch/write/VGPR/busy-cycle counters incl. the cold dispatch -> pod
// anomaly, not a code effect. Locking the verified champion:
// R21 base (packed v_pk_* math, depth-D MLP weight pipeline) +
// R24 early weight warm-up (te_w2/ip_w1/ip_w2 HBM->L2, overlapped with
// phase0+emb+layer1, sunk before the circuit).
// Layout: 256 thr = 4 waves, wave == ancilla s; m = (lane<<2)|r,
// lane bit (5-w) = wires 0..5, r bit1 = wire6, bit0 = wire7.

typedef float v2f __attribute__((ext_vector_type(2)));

__device__ __forceinline__ v2f pk_mul(v2f a, v2f b) {
  v2f d;
  asm("v_pk_mul_f32 %0, %1, %2" : "=v"(d) : "v"(a), "v"(b));
  return d;
}
__device__ __forceinline__ v2f pk_fma(v2f a, v2f b, v2f c) {
  v2f d;
  asm("v_pk_fma_f32 %0, %1, %2, %3" : "=v"(d) : "v"(a), "v"(b), "v"(c));
  return d;
}

// ---- VALU-only cross-lane xor exchange ----
template<int LM>
__device__ __forceinline__ float lane_partner(float x) {
  if constexpr (LM == 1) {
    return __int_as_float(__builtin_amdgcn_mov_dpp(__float_as_int(x), 0xB1, 0xF, 0xF, true));
  } else if constexpr (LM == 2) {
    return __int_as_float(__builtin_amdgcn_mov_dpp(__float_as_int(x), 0x4E, 0xF, 0xF, true));
  } else if constexpr (LM == 4) {
    int a = __builtin_amdgcn_mov_dpp(__float_as_int(x), 0x1B, 0xF, 0xF, true);   // xor3
    return __int_as_float(__builtin_amdgcn_mov_dpp(a, 0x141, 0xF, 0xF, true));   // xor7 -> net xor4
  } else if constexpr (LM == 8) {
    int a = __builtin_amdgcn_mov_dpp(__float_as_int(x), 0x141, 0xF, 0xF, true);  // xor7
    return __int_as_float(__builtin_amdgcn_mov_dpp(a, 0x140, 0xF, 0xF, true));   // xor15 -> net xor8
  } else if constexpr (LM == 16) {
#if __has_builtin(__builtin_amdgcn_permlane16_swap)
    unsigned xu = __float_as_uint(x);
    auto r = __builtin_amdgcn_permlane16_swap(xu, xu, false, false);
    return (__uint_as_float(r[0]) + __uint_as_float(r[1])) - x;
#else
    return __shfl_xor(x, 16, 64);
#endif
  } else {
#if __has_builtin(__builtin_amdgcn_permlane32_swap)
    unsigned xu = __float_as_uint(x);
    auto r = __builtin_amdgcn_permlane32_swap(xu, xu, false, false);
    return (__uint_as_float(r[0]) + __uint_as_float(r[1])) - x;
#else
    return __shfl_xor(x, 32, 64);
#endif
  }
}

template<int LM>
__device__ __forceinline__ float xor_sum(float x) {
  if constexpr (LM == 16) {
#if __has_builtin(__builtin_amdgcn_permlane16_swap)
    unsigned xu = __float_as_uint(x);
    auto r = __builtin_amdgcn_permlane16_swap(xu, xu, false, false);
    return __uint_as_float(r[0]) + __uint_as_float(r[1]);
#else
    return x + __shfl_xor(x, 16, 64);
#endif
  } else if constexpr (LM == 32) {
#if __has_builtin(__builtin_amdgcn_permlane32_swap)
    unsigned xu = __float_as_uint(x);
    auto r = __builtin_amdgcn_permlane32_swap(xu, xu, false, false);
    return __uint_as_float(r[0]) + __uint_as_float(r[1]);
#else
    return x + __shfl_xor(x, 32, 64);
#endif
  } else {
    return x + lane_partner<LM>(x);
  }
}

__device__ __forceinline__ float rdlane(float v, int idx) {
  return __int_as_float(__builtin_amdgcn_readlane(__float_as_int(v), idx));
}

__device__ __forceinline__ float2 cmul(float2 a, float2 b) {
  return make_float2(a.x*b.x - a.y*b.y, a.x*b.y + a.y*b.x);
}
__device__ __forceinline__ float2 cmulc(float2 a, float2 b) {  // a * conj(b)
  return make_float2(a.x*b.x + a.y*b.y, a.y*b.x - a.x*b.y);
}
__device__ __forceinline__ float2 cadd(float2 a, float2 b) {
  return make_float2(a.x + b.x, a.y + b.y);
}

struct SV { v2f q[4]; };   // q[r] = (re, im)

// ---------------- gate helpers (4 complex amps/lane, packed math) ----------------

template<int W>
__device__ __forceinline__ void ry_lane4(v2f* vv, int lane,
                                         float ct, float st, int idx, float sg) {
  float c = rdlane(ct, idx), s = sg * rdlane(st, idx);
  constexpr int LM = 1 << (5 - W);
  const float ls = (lane & LM) ? s : -s;
  v2f c2 = {c, c}, ls2 = {ls, ls};
#pragma unroll
  for (int r = 0; r < 4; ++r) {
    v2f p;
    p.x = lane_partner<LM>(vv[r].x);
    p.y = lane_partner<LM>(vv[r].y);
    vv[r] = pk_fma(ls2, p, pk_mul(c2, vv[r]));
  }
}

__device__ __forceinline__ void ry_reg6(v2f* vv, float ct, float st, int idx, float sg) {
  float c = rdlane(ct, idx), s = sg * rdlane(st, idx);
  v2f c2 = {c, c}, s2 = {s, s}, ns2 = {-s, -s};
#pragma unroll
  for (int k = 0; k < 2; ++k) {
    v2f a0 = vv[k], a1 = vv[k + 2];
    vv[k]     = pk_fma(ns2, a1, pk_mul(c2, a0));
    vv[k + 2] = pk_fma(s2,  a0, pk_mul(c2, a1));
  }
}

__device__ __forceinline__ void ry_reg7(v2f* vv, float ct, float st, int idx, float sg) {
  float c = rdlane(ct, idx), s = sg * rdlane(st, idx);
  v2f c2 = {c, c}, s2 = {s, s}, ns2 = {-s, -s};
#pragma unroll
  for (int k = 0; k < 4; k += 2) {
    v2f a0 = vv[k], a1 = vv[k + 1];
    vv[k]     = pk_fma(ns2, a1, pk_mul(c2, a0));
    vv[k + 1] = pk_fma(s2,  a0, pk_mul(c2, a1));
  }
}

template<int C, int T>
__device__ __forceinline__ void crx_ll4(v2f* vv, int lane,
                                        float ct, float st, int idx, float sg) {
  float c = rdlane(ct, idx), s = sg * rdlane(st, idx);
  constexpr int LC = 1 << (5 - C), LT = 1 << (5 - T);
  const bool act = (lane & LC) != 0;
  const float cp = act ? c : 1.f, sp = act ? s : 0.f;
  v2f cp2 = {cp, cp}, ssp2 = {sp, -sp};
#pragma unroll
  for (int r = 0; r < 4; ++r) {
    v2f p;
    p.x = lane_partner<LT>(vv[r].y);   // partner imag
    p.y = lane_partner<LT>(vv[r].x);   // partner real
    vv[r] = pk_fma(ssp2, p, pk_mul(cp2, vv[r]));
  }
}

template<int RB, int T>
__device__ __forceinline__ void crx_rc_lane(v2f* vv,
                                            float ct, float st, int idx, float sg) {
  float c = rdlane(ct, idx), s = sg * rdlane(st, idx);
  constexpr int LT = 1 << (5 - T);
  v2f c2 = {c, c}, ss2 = {s, -s};
#pragma unroll
  for (int r = 0; r < 4; ++r) {
    if (r & RB) {
      v2f p;
      p.x = lane_partner<LT>(vv[r].y);
      p.y = lane_partner<LT>(vv[r].x);
      vv[r] = pk_fma(ss2, p, pk_mul(c2, vv[r]));
    }
  }
}

template<int C, int TB>
__device__ __forceinline__ void crx_lc_reg(v2f* vv, int lane,
                                           float ct, float st, int idx, float sg) {
  float c = rdlane(ct, idx), s = sg * rdlane(st, idx);
  constexpr int LC = 1 << (5 - C);
  const bool act = (lane & LC) != 0;
  const float cp = act ? c : 1.f, sp = act ? s : 0.f;
  v2f cp2 = {cp, cp}, ssp2 = {sp, -sp};
#pragma unroll
  for (int x = 0; x < 4; ++x) {
    if (!(x & TB)) {
      const int y = x | TB;
      v2f ox = vv[x], oy = vv[y];
      v2f swx = {ox.y, ox.x}, swy = {oy.y, oy.x};
      vv[x] = pk_fma(ssp2, swy, pk_mul(cp2, ox));
      vv[y] = pk_fma(ssp2, swx, pk_mul(cp2, oy));
    }
  }
}

template<int CB, int TB>
__device__ __forceinline__ void crx_rr(v2f* vv,
                                       float ct, float st, int idx, float sg) {
  float c = rdlane(ct, idx), s = sg * rdlane(st, idx);
  constexpr int x = CB, y = CB | TB;
  v2f c2 = {c, c}, ss2 = {s, -s};
  v2f ox = vv[x], oy = vv[y];
  v2f swx = {ox.y, ox.x}, swy = {oy.y, oy.x};
  vv[x] = pk_fma(ss2, swy, pk_mul(c2, ox));
  vv[y] = pk_fma(ss2, swx, pk_mul(c2, oy));
}

// ---------------- sim14 layers: force-inlined (R3 structure) ----------------

__device__ __forceinline__ SV sim14_fwd(SV v, float ct, float st, int off) {
  const int lane = threadIdx.x & 63;
  v2f* vv = v.q;
  const float sg = 1.f;
  ry_lane4<0>(vv,lane,ct,st,off+0,sg); ry_lane4<1>(vv,lane,ct,st,off+1,sg);
  ry_lane4<2>(vv,lane,ct,st,off+2,sg); ry_lane4<3>(vv,lane,ct,st,off+3,sg);
  ry_lane4<4>(vv,lane,ct,st,off+4,sg); ry_lane4<5>(vv,lane,ct,st,off+5,sg);
  ry_reg6(vv,ct,st,off+6,sg);
  ry_reg7(vv,ct,st,off+7,sg);
  crx_rc_lane<1,0>(vv,ct,st,off+8,sg);        // (7,0)
  crx_rr<2,1>(vv,ct,st,off+9,sg);             // (6,7)
  crx_lc_reg<5,2>(vv,lane,ct,st,off+10,sg);   // (5,6)
  crx_ll4<4,5>(vv,lane,ct,st,off+11,sg); crx_ll4<3,4>(vv,lane,ct,st,off+12,sg);
  crx_ll4<2,3>(vv,lane,ct,st,off+13,sg); crx_ll4<1,2>(vv,lane,ct,st,off+14,sg);
  crx_ll4<0,1>(vv,lane,ct,st,off+15,sg);
  ry_lane4<0>(vv,lane,ct,st,off+16,sg); ry_lane4<1>(vv,lane,ct,st,off+17,sg);
  ry_lane4<2>(vv,lane,ct,st,off+18,sg); ry_lane4<3>(vv,lane,ct,st,off+19,sg);
  ry_lane4<4>(vv,lane,ct,st,off+20,sg); ry_lane4<5>(vv,lane,ct,st,off+21,sg);
  ry_reg6(vv,ct,st,off+22,sg);
  ry_reg7(vv,ct,st,off+23,sg);
  crx_rr<1,2>(vv,ct,st,off+24,sg);            // (7,6)
  crx_lc_reg<0,1>(vv,lane,ct,st,off+25,sg);   // (0,7)
  crx_ll4<1,0>(vv,lane,ct,st,off+26,sg); crx_ll4<2,1>(vv,lane,ct,st,off+27,sg);
  crx_ll4<3,2>(vv,lane,ct,st,off+28,sg); crx_ll4<4,3>(vv,lane,ct,st,off+29,sg);
  crx_ll4<5,4>(vv,lane,ct,st,off+30,sg);
  crx_rc_lane<2,5>(vv,ct,st,off+31,sg);       // (6,5)
  return v;
}

__device__ __forceinline__ SV sim14_adj(SV v, float ct, float st, int off) {
  const int lane = threadIdx.x & 63;
  v2f* vv = v.q;
  const float sg = -1.f;
  crx_rc_lane<2,5>(vv,ct,st,off+31,sg);       // (6,5)
  crx_ll4<5,4>(vv,lane,ct,st,off+30,sg); crx_ll4<4,3>(vv,lane,ct,st,off+29,sg);
  crx_ll4<3,2>(vv,lane,ct,st,off+28,sg); crx_ll4<2,1>(vv,lane,ct,st,off+27,sg);
  crx_ll4<1,0>(vv,lane,ct,st,off+26,sg);
  crx_lc_reg<0,1>(vv,lane,ct,st,off+25,sg);   // (0,7)
  crx_rr<1,2>(vv,ct,st,off+24,sg);            // (7,6)
  ry_reg7(vv,ct,st,off+23,sg);
  ry_reg6(vv,ct,st,off+22,sg);
  ry_lane4<5>(vv,lane,ct,st,off+21,sg); ry_lane4<4>(vv,lane,ct,st,off+20,sg);
  ry_lane4<3>(vv,lane,ct,st,off+19,sg); ry_lane4<2>(vv,lane,ct,st,off+18,sg);
  ry_lane4<1>(vv,lane,ct,st,off+17,sg); ry_lane4<0>(vv,lane,ct,st,off+16,sg);
  crx_ll4<0,1>(vv,lane,ct,st,off+15,sg); crx_ll4<1,2>(vv,lane,ct,st,off+14,sg);
  crx_ll4<2,3>(vv,lane,ct,st,off+13,sg); crx_ll4<3,4>(vv,lane,ct,st,off+12,sg);
  crx_ll4<4,5>(vv,lane,ct,st,off+11,sg);
  crx_lc_reg<5,2>(vv,lane,ct,st,off+10,sg);   // (5,6)
  crx_rr<2,1>(vv,ct,st,off+9,sg);             // (6,7)
  crx_rc_lane<1,0>(vv,ct,st,off+8,sg);        // (7,0)
  ry_reg7(vv,ct,st,off+7,sg);
  ry_reg6(vv,ct,st,off+6,sg);
  ry_lane4<5>(vv,lane,ct,st,off+5,sg); ry_lane4<4>(vv,lane,ct,st,off+4,sg);
  ry_lane4<3>(vv,lane,ct,st,off+3,sg); ry_lane4<2>(vv,lane,ct,st,off+2,sg);
  ry_lane4<1>(vv,lane,ct,st,off+1,sg); ry_lane4<0>(vv,lane,ct,st,off+0,sg);
  return v;
}

// ---------------- cooperative-row MLP layer, depth-D weight pipeline (R21) ----------------

template<int IN, int NP, int MODE, int D>
__device__ __forceinline__ void mlp_layer(const float* __restrict__ W,
    const float* __restrict__ bias, const float* xl, float* yl,
    int rbase, int lane)
{
  const int sub = lane & 7;
  const int g   = lane >> 3;
  constexpr int NIT = IN / 32;
  const float4* x4 = (const float4*)xl + sub;
  float4 e[NIT];
#pragma unroll
  for (int it = 0; it < NIT; ++it) e[it] = x4[it * 8];

  float4 wbuf[D][NIT];
#pragma unroll
  for (int d = 0; d < D; ++d) {
    const float4* wp = (const float4*)(W + (rbase + d * 8 + g) * IN) + sub;
#pragma unroll
    for (int it = 0; it < NIT; ++it) wbuf[d][it] = wp[it * 8];
  }

#pragma unroll
  for (int p = 0; p < NP; ++p) {
    constexpr int DD = D;   // keep p % DD compile-time under unroll
    v2f acc2 = {0.f, 0.f};
#pragma unroll
    for (int it = 0; it < NIT; ++it) {
      float4 w = wbuf[p % DD][it];
      v2f wa = {w.x, w.y}, wb = {w.z, w.w};
      v2f ea = {e[it].x, e[it].y}, eb = {e[it].z, e[it].w};
      acc2 = pk_fma(wa, ea, acc2);
      acc2 = pk_fma(wb, eb, acc2);
    }
    if (p + D < NP) {
      const float4* wn = (const float4*)(W + (rbase + (p + D) * 8 + g) * IN) + sub;
#pragma unroll
      for (int it = 0; it < NIT; ++it) wbuf[p % DD][it] = wn[it * 8];
    }
    float acc = acc2.x + acc2.y;
    acc = xor_sum<1>(acc);
    acc = xor_sum<2>(acc);
    acc = xor_sum<4>(acc);
    if (sub == 0) {
      const int row = rbase + p * 8 + g;
      float a = acc + bias[row];
      if constexpr (MODE == 0) {
        yl[row] = a / (1.f + __expf(-a));
      } else if constexpr (MODE == 1) {
        yl[row] = a;
      } else {
        float th = PI_F / (1.f + __expf(-a));   // theta/2 = pi * sigmoid(a)
        float sn, cn;
        __sincosf(th, &sn, &cn);
        ((float2*)yl)[row] = make_float2(cn, sn);
      }
    }
  }
}

// ---------------- main kernel: 256 threads = 4 waves, one batch elem/block ----------------

__global__ __launch_bounds__(256, 1) void qsvt_kernel(
    const float* __restrict__ z_t, const float* __restrict__ t,
    const float* __restrict__ te_w1, const float* __restrict__ te_b1,
    const float* __restrict__ te_w2, const float* __restrict__ te_b2,
    const float* __restrict__ ip_w1, const float* __restrict__ ip_b1,
    const float* __restrict__ ip_w2, const float* __restrict__ ip_b2,
    const float* __restrict__ prep_p, const float* __restrict__ sig,
    const float* __restrict__ qff,
    const float* __restrict__ A_obs, const float* __restrict__ B_obs,
    const float* __restrict__ D_obs,
    const float* __restrict__ head_w, const float* __restrict__ head_b,
    float* __restrict__ out)
{
  __shared__ __align__(16) float emb[128];
  __shared__ __align__(16) float y1[128];
  __shared__ __align__(16) float hbuf[256];
  __shared__ __align__(16) float h1[256];
  __shared__ __align__(16) float2 seltab[256];   // [s*64+g] -> (cos(th/2), sin(th/2))
  __shared__ __align__(16) float2 qtab2[32];
  __shared__ __align__(16) float2 sX1[16], sX2[16], sF[16], sa0[4];
  __shared__ __align__(16) float dumpR[4][256];
  __shared__ __align__(16) float dumpI[4][256];
  __shared__ float redbuf[NOBS][4];
  __shared__ float hdc[NOBS][3], hxc[NOBS][6], hyc[NOBS][6];
  __shared__ __align__(16) float shw[128 * NOBS];
  __shared__ __align__(16) float shb[128];
  extern __shared__ float4 dxw[];                // 2 x (256 R + 256 I) float4 = 16 KB

  const int tid  = threadIdx.x;
  const int lane = tid & 63;
  const int wv   = tid >> 6;   // 0..3
  const int s    = wv;         // ancilla value == wave
  const int b    = blockIdx.x;

  // ===== R24: early weight warm-up (HBM->L2, overlapped with phase0+emb+L1) =====
  // 9216 cachelines total: te_w2 (1024) + ip_w1 (4096) + ip_w2 (4096).
  // Partition 1/32 per block assuming mod-8 XCD round-robin (perf heuristic
  // only). 2 dword loads/thread, sunk before the circuit.
  float wtmp0, wtmp1;
  {
    const int chunk = (blockIdx.x >> 3) & 31;
    int l0 = chunk * 288 + tid;
    int l1 = l0 + 256;
    if (l0 >= 9216) l0 = 0;
    if (l1 >= 9216) l1 = 0;
    const float* a0 = (l0 < 1024) ? (te_w2 + (l0 << 4))
                    : (l0 < 5120) ? (ip_w1 + ((l0 - 1024) << 4))
                                  : (ip_w2 + ((l0 - 5120) << 4));
    const float* a1 = (l1 < 1024) ? (te_w2 + (l1 << 4))
                    : (l1 < 5120) ? (ip_w1 + ((l1 - 1024) << 4))
                                  : (ip_w2 + ((l1 - 5120) << 4));
    wtmp0 = *a0;
    wtmp1 = *a1;
  }

  // ===== Phase 0: wave 0 builds block-invariant ancilla matrices into LDS =====
  if (tid < 32) {
    float sn, cn;
    __sincosf(0.5f * qff[tid], &sn, &cn);
    qtab2[tid] = make_float2(cn, sn);
  }
  if (wv == 0) {
    float2 Ga[2][2][2], Gb[2][2][2];
    for (int ly = 0; ly < 2; ++ly)
      for (int qi = 0; qi < 2; ++qi) {
        float y = prep_p[ly*4 + qi*2 + 0], z = prep_p[ly*4 + qi*2 + 1];
        float cy, sy, cz, sz;
        __sincosf(0.5f*y, &sy, &cy);
        __sincosf(0.5f*z, &sz, &cz);
        float2 g00 = make_float2( cy*cz, -cy*sz);
        float2 g01 = make_float2(-sy*cz,  sy*sz);
        float2 g10 = make_float2( sy*cz,  sy*sz);
        float2 g11 = make_float2( cy*cz,  cy*sz);
        if (qi == 0) { Ga[ly][0][0]=g00; Ga[ly][0][1]=g01; Ga[ly][1][0]=g10; Ga[ly][1][1]=g11; }
        else         { Gb[ly][0][0]=g00; Gb[ly][0][1]=g01; Gb[ly][1][0]=g10; Gb[ly][1][1]=g11; }
      }
    float2 M[2][4][4];
    for (int ly = 0; ly < 2; ++ly) {
      float2 T[4][4];
      for (int i = 0; i < 4; ++i)
        for (int j = 0; j < 4; ++j)
          T[i][j] = cmul(Ga[ly][i>>1][j>>1], Gb[ly][i&1][j&1]);
      for (int j = 0; j < 4; ++j) {
        M[ly][0][j] = T[0][j]; M[ly][1][j] = T[1][j];
        M[ly][2][j] = T[3][j]; M[ly][3][j] = T[2][j];
      }
    }
    float2 U[4][4];
    for (int i = 0; i < 4; ++i)
      for (int j = 0; j < 4; ++j) {
        float2 acc = make_float2(0.f, 0.f);
        for (int kk = 0; kk < 4; ++kk) acc = cadd(acc, cmul(M[1][i][kk], M[0][kk][j]));
        U[i][j] = acc;
      }
    float c0n, s0n, c1, s1v, c2, s2v, c3, s3v;
    __sincosf(sig[0], &s0n, &c0n);
    __sincosf(sig[1], &s1v, &c1);
    __sincosf(sig[2], &s2v, &c2);
    __sincosf(sig[3], &s3v, &c3);
    if (lane < 16) {
      int i = lane >> 2, j = lane & 3;   // i = s (row), j = sp (col)
      float2 a1 = make_float2(0.f, 0.f), a2 = make_float2(0.f, 0.f);
      for (int k = 0; k < 4; ++k) {
        float2 tt = cmulc(U[i][k], U[j][k]);
        float sk = (k == 0) ? 1.f : -1.f;
        a1 = cadd(a1, cmul(tt, make_float2(c1, sk*s1v)));
        a2 = cadd(a2, cmul(tt, make_float2(c2, sk*s2v)));
      }
      sX1[lane] = a1;
      sX2[lane] = a2;
      float2 d3 = make_float2(c3, (i == 0) ? s3v : -s3v);
      sF[lane] = cmul(d3, make_float2(U[j][i].x, -U[j][i].y));
    }
    if (lane < 4) sa0[lane] = cmul(U[lane][0], make_float2(c0n, s0n));
  }

  // ===== Phase A: MLP (cooperative rows, 4 waves) =====
  if (tid < 128) {
    float fr = __expf(-9.210340371976184f * (float)(tid & 63) / 64.f);
    float arg = t[b] * fr;
    float sn, cn;
    __sincosf(arg, &sn, &cn);
    emb[tid] = (tid < 64) ? cn : sn;
  }
  __syncthreads();

  mlp_layer<128, 4, 0, 4>(te_w1, te_b1, emb, y1, wv * 32, lane);
  if (tid < 128) hbuf[tid] = z_t[b * 128 + tid];
  __syncthreads();

  mlp_layer<128, 4, 1, 4>(te_w2, te_b2, y1, hbuf + 128, wv * 32, lane);
  __syncthreads();

  mlp_layer<256, 8, 0, 3>(ip_w1, ip_b1, hbuf, h1, wv * 64, lane);
  __syncthreads();

  mlp_layer<256, 8, 2, 3>(ip_w2, ip_b2, h1, (float*)seltab, wv * 64, lane);

  // prefetch observable + head coefficients into LDS (off the tail path)
  if (tid < NOBS * 6)      { hxc[tid/6][tid%6] = A_obs[tid]; hyc[tid/6][tid%6] = B_obs[tid]; }
  else if (tid >= 64 && tid < 64 + NOBS*3) { int q = tid - 64; hdc[q/3][q%3] = 2.f * D_obs[(q/3)*4 + (q%3) + 1]; }
#pragma unroll
  for (int i = tid; i < 128*NOBS; i += 256) shw[i] = head_w[i];
  if (tid < 128) shb[tid] = head_b[tid];
  __syncthreads();  // seltab/coefs/matrices visible to all waves

  // per-wave angle tables in registers (lane g <-> gate g)
  float2 mycs = seltab[(s << 6) | lane];
  float selc = mycs.x, sels = mycs.y;
  float2 myq = qtab2[lane & 31];
  float qc = myq.x, qs = myq.y;

  // R24: sink the warm-up loads (long since completed)
  asm volatile("" :: "v"(wtmp0), "v"(wtmp1));

  // ===== Phase C: circuit. init = U*D0*|0..0> : only m=0 (lane0, r0) nonzero =====
  SV v;
#pragma unroll
  for (int r = 0; r < 4; ++r) { v.q[r].x = 0.f; v.q[r].y = 0.f; }
  if (lane == 0) {
    float2 a0 = sa0[s];
    v.q[0].x = a0.x; v.q[0].y = a0.y;
  }

  // ancilla mix through the parity-alternating exchange buffer (1 barrier each)
  auto ancmix = [&](const float2* R, int site) {
    float4* bufR = dxw + (site & 1) * 512;
    float4* bufI = bufR + 256;
    bufR[wv * 64 + lane] = make_float4(v.q[0].x, v.q[1].x, v.q[2].x, v.q[3].x);
    bufI[wv * 64 + lane] = make_float4(v.q[0].y, v.q[1].y, v.q[2].y, v.q[3].y);
    __syncthreads();
    float outr[4] = {0.f, 0.f, 0.f, 0.f}, outi[4] = {0.f, 0.f, 0.f, 0.f};
#pragma unroll
    for (int sp = 0; sp < 4; ++sp) {
      float4 Pr = bufR[sp * 64 + lane];
      float4 Pi = bufI[sp * 64 + lane];
      float2 Rr = R[sp];
      outr[0] += Rr.x*Pr.x - Rr.y*Pi.x;  outi[0] += Rr.x*Pi.x + Rr.y*Pr.x;
      outr[1] += Rr.x*Pr.y - Rr.y*Pi.y;  outi[1] += Rr.x*Pi.y + Rr.y*Pr.y;
      outr[2] += Rr.x*Pr.z - Rr.y*Pi.z;  outi[2] += Rr.x*Pi.z + Rr.y*Pr.z;
      outr[3] += Rr.x*Pr.w - Rr.y*Pi.w;  outi[3] += Rr.x*Pi.w + Rr.y*Pr.w;
    }
#pragma unroll
    for (int r = 0; r < 4; ++r) { v.q[r].x = outr[r]; v.q[r].y = outi[r]; }
  };
  // buffer-reuse safety: site 2 rewrites buffer 0 only after site 1's barrier,
  // which every wave reached after consuming its site-0 reads -> race-free.

  v = sim14_fwd(v, selc, sels, 0);
  v = sim14_fwd(v, selc, sels, 32);
  ancmix(&sX1[s << 2], 0);
  v = sim14_adj(v, selc, sels, 32);
  v = sim14_adj(v, selc, sels, 0);
  ancmix(&sX2[s << 2], 1);
  v = sim14_fwd(v, selc, sels, 0);
  v = sim14_fwd(v, selc, sels, 32);
  ancmix(&sF[s << 2], 2);
  v = sim14_fwd(v, qc, qs, 0);

  // ===== Phase D: dump state, observables =====
  // each wave writes and reads ONLY its own s-row -> intra-wave lgkmcnt
  // ordering suffices, no barrier needed before the obs reads.
  *(float4*)&dumpR[s][lane << 2] = make_float4(v.q[0].x, v.q[1].x, v.q[2].x, v.q[3].x);
  *(float4*)&dumpI[s][lane << 2] = make_float4(v.q[0].y, v.q[1].y, v.q[2].y, v.q[3].y);

#pragma unroll
  for (int w = 0; w < NOBS; ++w) {
    const int pb = 6 - w;  // wires (w, w+1) -> bits (7-w, 6-w) of m
    int g = lane;
    int ib = ((g >> pb) << (pb + 2)) | (g & ((1 << pb) - 1));
    float xr[4], xi[4];
#pragma unroll
    for (int i = 0; i < 4; ++i) { xr[i] = dumpR[s][ib + (i << pb)]; xi[i] = dumpI[s][ib + (i << pb)]; }
    float a = hdc[w][0] * (xr[0]*xr[0] + xi[0]*xi[0])
            + hdc[w][1] * (xr[1]*xr[1] + xi[1]*xi[1])
            + hdc[w][2] * (xr[2]*xr[2] + xi[2]*xi[2]);
    const int oi[6] = {1, 2, 2, 3, 3, 3};
    const int oj[6] = {0, 0, 1, 0, 1, 2};
#pragma unroll
    for (int k2 = 0; k2 < 6; ++k2) {
      int i = oi[k2], j = oj[k2];
      float rr = xr[i]*xr[j] + xi[i]*xi[j];   // Re(conj(v_i) v_j)
      float ii = xr[i]*xi[j] - xi[i]*xr[j];   // Im(conj(v_i) v_j)
      a += 2.f * (hxc[w][k2]*rr - hyc[w][k2]*ii);
    }
    a = xor_sum<32>(a);
    a = xor_sum<16>(a);
    a = xor_sum<8>(a);
    a = xor_sum<4>(a);
    a = xor_sum<2>(a);
    a = xor_sum<1>(a);
    if (lane == 0) redbuf[w][s] = a;
  }
  __syncthreads();

  // ===== Phase E: head =====
  if (tid < 128) {
    float acc = shb[tid];
#pragma unroll
    for (int w = 0; w < NOBS; ++w) {
      float ev = redbuf[w][0] + redbuf[w][1] + redbuf[w][2] + redbuf[w][3];
      acc += ev * shw[tid*NOBS + w];
    }
    out[b * 128 + tid] = acc;
  }
}

extern "C" void kernel_launch(void* const* d_in, const int* in_sizes, int n_in,
                              void* d_out, int out_size, void* d_ws, size_t ws_size,
                              hipStream_t stream) {
  (void)n_in; (void)out_size; (void)d_ws; (void)ws_size;
  const float* z_t    = (const float*)d_in[0];
  const float* t      = (const float*)d_in[1];
  const float* te_w1  = (const float*)d_in[2];
  const float* te_b1  = (const float*)d_in[3];
  const float* te_w2  = (const float*)d_in[4];
  const float* te_b2  = (const float*)d_in[5];
  const float* ip_w1  = (const float*)d_in[6];
  const float* ip_b1  = (const float*)d_in[7];
  const float* ip_w2  = (const float*)d_in[8];
  const float* ip_b2  = (const float*)d_in[9];
  const float* prep_p = (const float*)d_in[10];
  const float* sig    = (const float*)d_in[11];
  const float* qff    = (const float*)d_in[12];
  const float* A_obs  = (const float*)d_in[13];
  const float* B_obs  = (const float*)d_in[14];
  const float* D_obs  = (const float*)d_in[15];
  const float* head_w = (const float*)d_in[16];
  const float* head_b = (const float*)d_in[17];
  float* out = (float*)d_out;

  int B = in_sizes[1];  // t is (B,)
  size_t dyn = 2 * 512 * sizeof(float4);
  qsvt_kernel<<<B, 256, dyn, stream>>>(
      z_t, t, te_w1, te_b1, te_w2, te_b2, ip_w1, ip_b1, ip_w2, ip_b2,
      prep_p, sig, qff, A_obs, B_obs, D_obs, head_w, head_b, out);
}